// Round 2
// baseline (217.939 us; speedup 1.0000x reference)
//
#include <hip/hip_runtime.h>
#include <hip/hip_bf16.h>

#define H 1024
#define B 64
#define LT 16

// Kernel A: u[b,h] = sum_k hidden[b,k]*W[k,h];  c[b] = hidden[b]·bias
// grid (H/256, B/4), block 256. 4 accumulators -> ILP 4, W re-read 16x (L2).
__global__ __launch_bounds__(256) void proj_hidden_kernel(
    const float* __restrict__ hidden,   // [B, H]
    const float* __restrict__ W,        // [H, H] (W[k*H + h])
    const float* __restrict__ bias,     // [H]
    float* __restrict__ u,              // [B, H]
    float* __restrict__ c)              // [B]
{
    const int h  = blockIdx.x * 256 + threadIdx.x;
    const int b0 = blockIdx.y * 4;
    const float* hb0 = hidden + (size_t)(b0 + 0) * H;
    const float* hb1 = hidden + (size_t)(b0 + 1) * H;
    const float* hb2 = hidden + (size_t)(b0 + 2) * H;
    const float* hb3 = hidden + (size_t)(b0 + 3) * H;

    float a0 = 0.f, a1 = 0.f, a2 = 0.f, a3 = 0.f;
    #pragma unroll 4
    for (int k = 0; k < H; ++k) {
        float wv = W[(size_t)k * H + h];   // coalesced across threads
        a0 += hb0[k] * wv;                 // hb*: wave-uniform scalar loads
        a1 += hb1[k] * wv;
        a2 += hb2[k] * wv;
        a3 += hb3[k] * wv;
    }
    u[(size_t)(b0 + 0) * H + h] = a0;
    u[(size_t)(b0 + 1) * H + h] = a1;
    u[(size_t)(b0 + 2) * H + h] = a2;
    u[(size_t)(b0 + 3) * H + h] = a3;

    // c[b] for the 4 b's of this tile: one wave each
    if (blockIdx.x == 0) {
        const int wv_ = threadIdx.x >> 6;
        const int lane = threadIdx.x & 63;
        const int b = b0 + wv_;
        const float* hb = hidden + (size_t)b * H;
        float s = 0.f;
        #pragma unroll 4
        for (int k = lane; k < H; k += 64) s += hb[k] * bias[k];
        for (int off = 32; off > 0; off >>= 1) s += __shfl_down(s, off, 64);
        if (lane == 0) c[b] = s;
    }
}

// Kernel B: streaming energies. grid (L/LT, B), block 256 (4 waves x 4 rows).
// e[b*L + l] = u[b]·enc[l,b] + c[b].  u row held in registers, reused 16x.
__global__ __launch_bounds__(256) void energies_kernel(
    const float* __restrict__ enc,   // [L, B, H]
    const float* __restrict__ u,     // [B, H]
    const float* __restrict__ c,     // [B]
    float* __restrict__ e,           // [B, L]
    int L)
{
    const int lt   = blockIdx.x;
    const int b    = blockIdx.y;
    const int wave = threadIdx.x >> 6;
    const int lane = threadIdx.x & 63;

    const float4* u4 = (const float4*)(u + (size_t)b * H);
    const float4 uv0 = u4[lane];
    const float4 uv1 = u4[lane + 64];
    const float4 uv2 = u4[lane + 128];
    const float4 uv3 = u4[lane + 192];
    const float  cb  = c[b];

    #pragma unroll
    for (int i = 0; i < 4; ++i) {
        const int l = lt * LT + wave * 4 + i;
        if (l >= L) break;
        const float4* e4 = (const float4*)(enc + ((size_t)l * B + b) * H);
        const float4 v0 = e4[lane];
        const float4 v1 = e4[lane + 64];
        const float4 v2 = e4[lane + 128];
        const float4 v3 = e4[lane + 192];
        float acc = v0.x*uv0.x + v0.y*uv0.y + v0.z*uv0.z + v0.w*uv0.w
                  + v1.x*uv1.x + v1.y*uv1.y + v1.z*uv1.z + v1.w*uv1.w
                  + v2.x*uv2.x + v2.y*uv2.y + v2.z*uv2.z + v2.w*uv2.w
                  + v3.x*uv3.x + v3.y*uv3.y + v3.z*uv3.z + v3.w*uv3.w;
        for (int off = 32; off > 0; off >>= 1) acc += __shfl_down(acc, off, 64);
        if (lane == 0) e[(size_t)b * L + l] = acc + cb;
    }
}

// Kernel C: softmax over b (the batch axis) for each l. Thread owns one l.
// All e reads and out writes are coalesced across adjacent-l threads.
__global__ __launch_bounds__(64) void softmax_kernel(
    const float* __restrict__ e,     // [B, L]
    float* __restrict__ out,         // [B, 1, L] flat
    int L)
{
    const int l = blockIdx.x * 64 + threadIdx.x;
    if (l >= L) return;
    float ev[B];
    float m = -INFINITY;
    #pragma unroll
    for (int b = 0; b < B; ++b) {
        ev[b] = e[(size_t)b * L + l];
        m = fmaxf(m, ev[b]);
    }
    float s = 0.f;
    #pragma unroll
    for (int b = 0; b < B; ++b) {
        ev[b] = expf(ev[b] - m);
        s += ev[b];
    }
    const float inv = 1.f / s;
    #pragma unroll
    for (int b = 0; b < B; ++b)
        out[(size_t)b * L + l] = ev[b] * inv;
}

extern "C" void kernel_launch(void* const* d_in, const int* in_sizes, int n_in,
                              void* d_out, int out_size, void* d_ws, size_t ws_size,
                              hipStream_t stream) {
    const float* hidden = (const float*)d_in[0];  // [1, 64, 1024]
    const float* enc    = (const float*)d_in[1];  // [L, 64, 1024]
    const float* W      = (const float*)d_in[2];  // [1024, 1024]
    const float* bias   = (const float*)d_in[3];  // [1024]
    float* out = (float*)d_out;                   // [64, 1, L]

    const int L = in_sizes[1] / (B * H);          // 2048

    float* u = (float*)d_ws;                      // B*H floats
    float* c = u + (size_t)B * H;                 // B floats
    float* e = c + B;                             // B*L floats (16B-aligned: (B*H+B)*4 % 16 == 0)

    dim3 gridA(H / 256, B / 4);
    proj_hidden_kernel<<<gridA, 256, 0, stream>>>(hidden, W, bias, u, c);

    dim3 gridB((L + LT - 1) / LT, B);
    energies_kernel<<<gridB, 256, 0, stream>>>(enc, u, c, e, L);

    softmax_kernel<<<(L + 63) / 64, 64, 0, stream>>>(e, out, L);
}

// Round 3
// 128.433 us; speedup vs baseline: 1.6969x; 1.6969x over previous
//
#include <hip/hip_runtime.h>
#include <hip/hip_bf16.h>

#define H 1024
#define B 64
#define KC 8            // k-chunks in A1
#define KLEN (H / KC)   // 128
#define LT 4            // l's per block in kernel B

// A1: part[kc][b][h] = sum_{k in chunk kc} hidden[b,k] * W[k,h]
// grid (B, KC), block 256. Each thread owns 4 h's (float4). W row loads are
// float4-coalesced (wave covers 4KB/instr); hidden[b,k] is wave-uniform (s_load).
__global__ __launch_bounds__(256) void projA1(
    const float* __restrict__ hidden,   // [B, H]
    const float* __restrict__ W,        // [H, H]
    float* __restrict__ part)           // [KC, B, H]
{
    const int b  = blockIdx.x;
    const int kc = blockIdx.y;
    const int t  = threadIdx.x;
    const float* hb = hidden + (size_t)b * H + (size_t)kc * KLEN;
    const float4* Wr = (const float4*)(W + (size_t)kc * KLEN * H) + t;

    float4 acc = {0.f, 0.f, 0.f, 0.f};
    #pragma unroll 8
    for (int k = 0; k < KLEN; ++k) {
        const float  s = hb[k];
        const float4 w = Wr[(size_t)k * (H / 4)];
        acc.x += s * w.x; acc.y += s * w.y; acc.z += s * w.z; acc.w += s * w.w;
    }
    ((float4*)(part + ((size_t)kc * B + b) * H))[t] = acc;
}

// A2: u[b,h] = sum_kc part[kc][b][h];  c[b] = hidden[b]·bias. grid (B), block 256.
__global__ __launch_bounds__(256) void projA2(
    const float* __restrict__ part,     // [KC, B, H]
    const float* __restrict__ hidden,   // [B, H]
    const float* __restrict__ bias,     // [H]
    float* __restrict__ u,              // [B, H]
    float* __restrict__ c)              // [B]
{
    const int b = blockIdx.x;
    const int t = threadIdx.x;

    float4 a = {0.f, 0.f, 0.f, 0.f};
    #pragma unroll
    for (int kc = 0; kc < KC; ++kc) {
        const float4 p = ((const float4*)(part + ((size_t)kc * B + b) * H))[t];
        a.x += p.x; a.y += p.y; a.z += p.z; a.w += p.w;
    }
    ((float4*)(u + (size_t)b * H))[t] = a;

    float s = 0.f;
    #pragma unroll
    for (int j = 0; j < H / 256; ++j)
        s += hidden[(size_t)b * H + t + j * 256] * bias[t + j * 256];
    __shared__ float red[256];
    red[t] = s;
    __syncthreads();
    for (int st = 128; st > 0; st >>= 1) {
        if (t < st) red[t] += red[t + st];
        __syncthreads();
    }
    if (t == 0) c[b] = red[0];
}

// B: e[b*L + l] = u[b]·enc[l,b] + c[b]. grid (L/LT), block 1024 (16 waves).
// Block reads a contiguous LT*256KB enc window; wave w owns b in [4w,4w+4),
// holding those u rows in registers (reused across LT l's).
__global__ __launch_bounds__(1024) void energiesB(
    const float* __restrict__ enc,   // [L, B, H]
    const float* __restrict__ u,     // [B, H]
    const float* __restrict__ c,     // [B]
    float* __restrict__ e,           // [B, L]
    int L)
{
    const int l0   = blockIdx.x * LT;
    const int wave = threadIdx.x >> 6;
    const int lane = threadIdx.x & 63;
    const int b0   = wave * 4;

    float4 uv[4][4];
    float  cv[4];
    #pragma unroll
    for (int j = 0; j < 4; ++j) {
        const float4* u4 = (const float4*)(u + (size_t)(b0 + j) * H);
        #pragma unroll
        for (int q = 0; q < 4; ++q) uv[j][q] = u4[lane + q * 64];
        cv[j] = c[b0 + j];
    }

    #pragma unroll 1
    for (int i = 0; i < LT; ++i) {
        const int l = l0 + i;
        if (l >= L) break;
        #pragma unroll
        for (int j = 0; j < 4; ++j) {
            const int b = b0 + j;
            const float4* e4 = (const float4*)(enc + ((size_t)l * B + b) * H);
            float acc = 0.f;
            #pragma unroll
            for (int q = 0; q < 4; ++q) {
                const float4 v = e4[lane + q * 64];
                acc += v.x * uv[j][q].x + v.y * uv[j][q].y
                     + v.z * uv[j][q].z + v.w * uv[j][q].w;
            }
            for (int off = 32; off > 0; off >>= 1) acc += __shfl_down(acc, off, 64);
            if (lane == 0) e[(size_t)b * L + l] = acc + cv[j];
        }
    }
}

// C: softmax over b for each l. Thread owns one l; e reads coalesced per b.
__global__ __launch_bounds__(256) void softmaxC(
    const float* __restrict__ e,     // [B, L]
    float* __restrict__ out,         // [B, 1, L] flat
    int L)
{
    const int l = blockIdx.x * 256 + threadIdx.x;
    if (l >= L) return;
    float ev[B];
    float m = -INFINITY;
    #pragma unroll
    for (int b = 0; b < B; ++b) {
        ev[b] = e[(size_t)b * L + l];
        m = fmaxf(m, ev[b]);
    }
    float s = 0.f;
    #pragma unroll
    for (int b = 0; b < B; ++b) {
        ev[b] = __expf(ev[b] - m);
        s += ev[b];
    }
    const float inv = 1.f / s;
    #pragma unroll
    for (int b = 0; b < B; ++b)
        out[(size_t)b * L + l] = ev[b] * inv;
}

extern "C" void kernel_launch(void* const* d_in, const int* in_sizes, int n_in,
                              void* d_out, int out_size, void* d_ws, size_t ws_size,
                              hipStream_t stream) {
    const float* hidden = (const float*)d_in[0];  // [1, 64, 1024]
    const float* enc    = (const float*)d_in[1];  // [L, 64, 1024]
    const float* W      = (const float*)d_in[2];  // [1024, 1024]
    const float* bias   = (const float*)d_in[3];  // [1024]
    float* out = (float*)d_out;                   // [64, 1, L]

    const int L = in_sizes[1] / (B * H);          // 2048

    float* part = (float*)d_ws;                   // KC*B*H floats (2 MiB)
    float* u    = part + (size_t)KC * B * H;      // B*H floats
    float* c    = u + (size_t)B * H;              // B floats
    float* e    = c + B;                          // B*L floats (16B-aligned)

    dim3 gridA1(B, KC);
    projA1<<<gridA1, 256, 0, stream>>>(hidden, W, part);

    projA2<<<B, 256, 0, stream>>>(part, hidden, bias, u, c);

    energiesB<<<(L + LT - 1) / LT, 1024, 0, stream>>>(enc, u, c, e, L);

    softmaxC<<<(L + 255) / 256, 256, 0, stream>>>(e, out, L);
}

// Round 4
// 116.243 us; speedup vs baseline: 1.8749x; 1.1049x over previous
//
#include <hip/hip_runtime.h>
#include <hip/hip_bf16.h>

#define H 1024
#define B 64
#define KC 8            // k-chunks in A1
#define KLEN (H / KC)   // 128
#define LT 4            // l's per block in kernel B

// A1: part[kc][b][h] = sum_{k in chunk kc} hidden[b,k] * W[k,h]
// grid (B/2, KC), block 256. 2 b's per block halves W re-reads (32x total).
__global__ __launch_bounds__(256) void projA1(
    const float* __restrict__ hidden,   // [B, H]
    const float* __restrict__ W,        // [H, H]
    float* __restrict__ part)           // [KC, B, H]
{
    const int b0 = blockIdx.x * 2;
    const int kc = blockIdx.y;
    const int t  = threadIdx.x;
    const float* h0 = hidden + (size_t)b0 * H + (size_t)kc * KLEN;
    const float* h1 = h0 + H;
    const float4* Wr = (const float4*)(W + (size_t)kc * KLEN * H) + t;

    float4 a0 = {0.f, 0.f, 0.f, 0.f};
    float4 a1 = {0.f, 0.f, 0.f, 0.f};
    #pragma unroll 8
    for (int k = 0; k < KLEN; ++k) {
        const float4 w = Wr[(size_t)k * (H / 4)];
        const float s0 = h0[k];
        const float s1 = h1[k];
        a0.x += s0 * w.x; a0.y += s0 * w.y; a0.z += s0 * w.z; a0.w += s0 * w.w;
        a1.x += s1 * w.x; a1.y += s1 * w.y; a1.z += s1 * w.z; a1.w += s1 * w.w;
    }
    ((float4*)(part + ((size_t)kc * B + b0) * H))[t]     = a0;
    ((float4*)(part + ((size_t)kc * B + b0 + 1) * H))[t] = a1;
}

// A2: u[b,h] = sum_kc part[kc][b][h];  c[b] = hidden[b]·bias. grid (B), block 256.
__global__ __launch_bounds__(256) void projA2(
    const float* __restrict__ part,     // [KC, B, H]
    const float* __restrict__ hidden,   // [B, H]
    const float* __restrict__ bias,     // [H]
    float* __restrict__ u,              // [B, H]
    float* __restrict__ c)              // [B]
{
    const int b = blockIdx.x;
    const int t = threadIdx.x;

    float4 a = {0.f, 0.f, 0.f, 0.f};
    #pragma unroll
    for (int kc = 0; kc < KC; ++kc) {
        const float4 p = ((const float4*)(part + ((size_t)kc * B + b) * H))[t];
        a.x += p.x; a.y += p.y; a.z += p.z; a.w += p.w;
    }
    ((float4*)(u + (size_t)b * H))[t] = a;

    float s = 0.f;
    #pragma unroll
    for (int j = 0; j < H / 256; ++j)
        s += hidden[(size_t)b * H + t + j * 256] * bias[t + j * 256];
    __shared__ float red[256];
    red[t] = s;
    __syncthreads();
    for (int st = 128; st > 0; st >>= 1) {
        if (t < st) red[t] += red[t + st];
        __syncthreads();
    }
    if (t == 0) c[b] = red[0];
}

// B (fused): energies + softmax-over-b + output write. grid (L/LT), block 1024.
// Block reads a contiguous LT*256KB enc window; wave w owns b in [4w,4w+4),
// holding those u rows in registers. Softmax over b is block-local.
__global__ __launch_bounds__(1024) void energy_softmax_fused(
    const float* __restrict__ enc,   // [L, B, H]
    const float* __restrict__ u,     // [B, H]
    const float* __restrict__ c,     // [B]
    float* __restrict__ out,         // [B, 1, L] flat
    int L)
{
    const int l0   = blockIdx.x * LT;
    const int wave = threadIdx.x >> 6;
    const int lane = threadIdx.x & 63;
    const int b0   = wave * 4;

    __shared__ float e_s[LT][B];

    float4 uv[4][4];
    float  cv[4];
    #pragma unroll
    for (int j = 0; j < 4; ++j) {
        const float4* u4 = (const float4*)(u + (size_t)(b0 + j) * H);
        #pragma unroll
        for (int q = 0; q < 4; ++q) uv[j][q] = u4[lane + q * 64];
        cv[j] = c[b0 + j];
    }

    #pragma unroll 1
    for (int i = 0; i < LT; ++i) {
        const int l = l0 + i;
        #pragma unroll
        for (int j = 0; j < 4; ++j) {
            const int b = b0 + j;
            const float4* e4 = (const float4*)(enc + ((size_t)l * B + b) * H);
            float acc = 0.f;
            #pragma unroll
            for (int q = 0; q < 4; ++q) {
                const float4 v = e4[lane + q * 64];
                acc += v.x * uv[j][q].x + v.y * uv[j][q].y
                     + v.z * uv[j][q].z + v.w * uv[j][q].w;
            }
            for (int off = 32; off > 0; off >>= 1) acc += __shfl_down(acc, off, 64);
            if (lane == 0) e_s[i][b] = acc + cv[j];
        }
    }
    __syncthreads();

    // softmax over b: wave i handles l0+i, lane = b
    if (wave < LT) {
        const float e = e_s[wave][lane];
        float m = e;
        #pragma unroll
        for (int off = 32; off > 0; off >>= 1) m = fmaxf(m, __shfl_xor(m, off, 64));
        const float ex = __expf(e - m);
        float s = ex;
        #pragma unroll
        for (int off = 32; off > 0; off >>= 1) s += __shfl_xor(s, off, 64);
        e_s[wave][lane] = ex / s;
    }
    __syncthreads();

    // write: thread t<256 -> (b = t>>2, li = t&3); 16B-contiguous per b
    if (threadIdx.x < B * LT) {
        const int b  = threadIdx.x >> 2;
        const int li = threadIdx.x & 3;
        out[(size_t)b * L + l0 + li] = e_s[li][b];
    }
}

extern "C" void kernel_launch(void* const* d_in, const int* in_sizes, int n_in,
                              void* d_out, int out_size, void* d_ws, size_t ws_size,
                              hipStream_t stream) {
    const float* hidden = (const float*)d_in[0];  // [1, 64, 1024]
    const float* enc    = (const float*)d_in[1];  // [L, 64, 1024]
    const float* W      = (const float*)d_in[2];  // [1024, 1024]
    const float* bias   = (const float*)d_in[3];  // [1024]
    float* out = (float*)d_out;                   // [64, 1, L]

    const int L = in_sizes[1] / (B * H);          // 2048

    float* part = (float*)d_ws;                   // KC*B*H floats (2 MiB)
    float* u    = part + (size_t)KC * B * H;      // B*H floats
    float* c    = u + (size_t)B * H;              // B floats

    dim3 gridA1(B / 2, KC);
    projA1<<<gridA1, 256, 0, stream>>>(hidden, W, part);

    projA2<<<B, 256, 0, stream>>>(part, hidden, bias, u, c);

    energy_softmax_fused<<<L / LT, 1024, 0, stream>>>(enc, u, c, out, L);
}